// Round 1
// baseline (694.774 us; speedup 1.0000x reference)
//
#include <hip/hip_runtime.h>
#include <hip/hip_bf16.h>

#define FDIM 128
#define NLEV 4
#define NT   64   // nodes per transform block

typedef unsigned int  u32;
typedef unsigned short u16;

__device__ __forceinline__ float bf_lo(u32 p) { return __uint_as_float(p << 16); }
__device__ __forceinline__ float bf_hi(u32 p) { return __uint_as_float(p & 0xffff0000u); }
__device__ __forceinline__ u16 f2bf(float f) {
    u32 u = __float_as_uint(f);
    u32 r = (u + 0x7fffu + ((u >> 16) & 1u)) >> 16;   // round-nearest-even
    return (u16)r;
}

// ---- K1: bin nodes by hierarchy level (order within bin is irrelevant) ----
__global__ void bin_kernel(const int* __restrict__ lv, int* __restrict__ cnt,
                           int* __restrict__ bin, int N) {
    int n = blockIdx.x * blockDim.x + threadIdx.x;
    if (n >= N) return;
    int l = lv[n];
    if (l >= 0 && l < NLEV) {
        int pos = atomicAdd(&cnt[l], 1);
        bin[l * N + pos] = n;
    }
}

// ---- K2: out = X ----
__global__ void copy_kernel(const float4* __restrict__ src, float4* __restrict__ dst, int n4) {
    int i = blockIdx.x * blockDim.x + threadIdx.x;
    int stride = gridDim.x * blockDim.x;
    for (; i < n4; i += stride) dst[i] = src[i];
}

// ---- K3: Y[n] = bf16( 0.2*(X[n] @ W[l].T + b[l]) ) for binned nodes ----
__global__ __launch_bounds__(256) void transform_kernel(
    const float* __restrict__ X, const float* __restrict__ Wg,
    const float* __restrict__ bg, const int* __restrict__ cnt,
    const int* __restrict__ bin, u16* __restrict__ Y, int N, int blocksPerLevel)
{
    // Wt[j][f] = bf16(W[l][f][j]); row stride 136 u16 = 272B (16B-aligned, breaks pow2 banks)
    __shared__ __align__(16) u16 Wt[FDIM][136];
    // Xt[j][n] = bf16(X[node_n][j]); row stride 68 u16 = 136B (8B-aligned)
    __shared__ __align__(16) u16 Xt[FDIM][NT + 4];
    __shared__ int nodes_s[NT];

    int l     = blockIdx.x / blocksPerLevel;
    int chunk = blockIdx.x % blocksPerLevel;
    int m_total = cnt[l];
    int base = chunk * NT;
    if (base >= m_total) return;
    int m = min(NT, m_total - base);
    int t = threadIdx.x;

    if (t < NT) nodes_s[t] = (t < m) ? bin[l * N + base + t] : -1;
    __syncthreads();

    // stage W[l] transposed: 16384 elems, 64 per thread, coalesced global reads
    const float* Wl = Wg + l * FDIM * FDIM;
    #pragma unroll
    for (int k = 0; k < (FDIM * FDIM) / 256; ++k) {
        int flat = t + k * 256;
        int f = flat >> 7, j = flat & 127;
        Wt[j][f] = f2bf(Wl[flat]);
    }
    // stage X tile transposed: NT*128 elems, 32 per thread
    #pragma unroll
    for (int k = 0; k < (NT * FDIM) / 256; ++k) {
        int flat = t + k * 256;
        int nl = flat >> 7, j = flat & 127;
        int node = nodes_s[nl];
        float v = (node >= 0) ? X[node * FDIM + j] : 0.0f;
        Xt[j][nl] = f2bf(v);
    }
    __syncthreads();

    int ng = t >> 4;          // 0..15 -> nodes n0..n0+3
    int fg = t & 15;          // 0..15 -> feats f0..f0+7
    int n0 = ng * 4, f0 = fg * 8;

    float acc[4][8];
    #pragma unroll
    for (int a = 0; a < 4; ++a)
        #pragma unroll
        for (int c = 0; c < 8; ++c) acc[a][c] = 0.0f;

    for (int j = 0; j < FDIM; ++j) {
        uint2 xp = *(const uint2*)&Xt[j][n0];   // 4 bf16 (broadcast-heavy, conflict-free)
        uint4 wp = *(const uint4*)&Wt[j][f0];   // 8 bf16, 256B contiguous across lanes
        float xv[4] = { bf_lo(xp.x), bf_hi(xp.x), bf_lo(xp.y), bf_hi(xp.y) };
        float wv[8] = { bf_lo(wp.x), bf_hi(wp.x), bf_lo(wp.y), bf_hi(wp.y),
                        bf_lo(wp.z), bf_hi(wp.z), bf_lo(wp.w), bf_hi(wp.w) };
        #pragma unroll
        for (int a = 0; a < 4; ++a)
            #pragma unroll
            for (int c = 0; c < 8; ++c)
                acc[a][c] = fmaf(xv[a], wv[c], acc[a][c]);
    }

    const float* bl = bg + l * FDIM;
    float bv[8];
    #pragma unroll
    for (int c = 0; c < 8; ++c) bv[c] = bl[f0 + c];

    #pragma unroll
    for (int a = 0; a < 4; ++a) {
        int node = nodes_s[n0 + a];
        if (node < 0) continue;
        u32 pk[4];
        #pragma unroll
        for (int c = 0; c < 4; ++c) {
            u16 e0 = f2bf(0.2f * (acc[a][2 * c]     + bv[2 * c]));
            u16 e1 = f2bf(0.2f * (acc[a][2 * c + 1] + bv[2 * c + 1]));
            pk[c] = (u32)e0 | ((u32)e1 << 16);
        }
        uint4 v = make_uint4(pk[0], pk[1], pk[2], pk[3]);
        *(uint4*)&Y[node * FDIM + f0] = v;   // 16B store, aligned
    }
}

// ---- K4: for each edge, if lv[hi] > lv[lo]: out[hi] += Y[lo] (atomic) ----
__global__ __launch_bounds__(256) void scatter_kernel(
    const int* __restrict__ edges, const int* __restrict__ lv,
    const u32* __restrict__ Y2, float* __restrict__ out, int E)
{
    int gid = blockIdx.x * blockDim.x + threadIdx.x;
    int e = gid >> 6;
    int lane = gid & 63;
    if (e >= E) return;
    int lo = edges[2 * e];
    int hi = edges[2 * e + 1];
    int ll = lv[lo];
    int hl = lv[hi];
    if (hl <= ll) return;   // valid <=> lv[hi] > lv[lo] (implies ll < 4)
    u32 p = Y2[lo * (FDIM / 2) + lane];       // 2 bf16, already scaled by 0.2
    float v0 = bf_lo(p);
    float v1 = bf_hi(p);
    float* dst = out + hi * FDIM + lane * 2;
    atomicAdd(dst, v0);
    atomicAdd(dst + 1, v1);
}

extern "C" void kernel_launch(void* const* d_in, const int* in_sizes, int n_in,
                              void* d_out, int out_size, void* d_ws, size_t ws_size,
                              hipStream_t stream) {
    const float* X  = (const float*)d_in[0];
    const float* Wg = (const float*)d_in[1];
    const float* bg = (const float*)d_in[2];
    const int*   lv = (const int*)d_in[3];
    const int*   eg = (const int*)d_in[4];
    float* out = (float*)d_out;

    int N = in_sizes[3];
    int E = in_sizes[4] / 2;

    // workspace layout: Y (bf16, N*F) | cnt (8 ints) | bin (4*N ints)
    u16* Y   = (u16*)d_ws;
    char* p  = (char*)d_ws + (size_t)N * FDIM * sizeof(u16);
    int* cnt = (int*)p;
    int* bin = (int*)(p + 32);

    hipMemsetAsync(cnt, 0, 8 * sizeof(int), stream);

    bin_kernel<<<(N + 255) / 256, 256, 0, stream>>>(lv, cnt, bin, N);

    int n4 = (N * FDIM) / 4;
    copy_kernel<<<2048, 256, 0, stream>>>((const float4*)X, (float4*)out, n4);

    int blocksPerLevel = (N + NT - 1) / NT;
    transform_kernel<<<NLEV * blocksPerLevel, 256, 0, stream>>>(
        X, Wg, bg, cnt, bin, Y, N, blocksPerLevel);

    int totalThreads = E * 64;
    scatter_kernel<<<(totalThreads + 255) / 256, 256, 0, stream>>>(
        eg, lv, (const u32*)Y, out, E);
}

// Round 2
// 267.668 us; speedup vs baseline: 2.5957x; 2.5957x over previous
//
#include <hip/hip_runtime.h>
#include <hip/hip_bf16.h>

#define FDIM 128
#define NLEV 4
#define NT   64   // nodes per transform block

typedef unsigned int  u32;
typedef unsigned short u16;

__device__ __forceinline__ float bf_lo(u32 p) { return __uint_as_float(p << 16); }
__device__ __forceinline__ float bf_hi(u32 p) { return __uint_as_float(p & 0xffff0000u); }
__device__ __forceinline__ u16 f2bf(float f) {
    u32 u = __float_as_uint(f);
    u32 r = (u + 0x7fffu + ((u >> 16) & 1u)) >> 16;   // round-nearest-even
    return (u16)r;
}

// ---- K1: bin nodes by level. Two-level: LDS histogram -> 4 global atomics/block ----
__global__ __launch_bounds__(256) void bin_kernel(const int* __restrict__ lv,
                                                  int* __restrict__ cnt,
                                                  int* __restrict__ bin, int N) {
    __shared__ int lcnt[NLEV];
    __shared__ int lbase[NLEV];
    int t = threadIdx.x;
    if (t < NLEV) lcnt[t] = 0;
    __syncthreads();
    int n = blockIdx.x * blockDim.x + t;
    int l = -1, pos = 0;
    if (n < N) {
        l = lv[n];
        if (l >= 0 && l < NLEV) pos = atomicAdd(&lcnt[l], 1);  // LDS atomic, cheap
        else l = -1;
    }
    __syncthreads();
    if (t < NLEV) lbase[t] = lcnt[t] ? atomicAdd(&cnt[t], lcnt[t]) : 0;  // 4 global atomics/block
    __syncthreads();
    if (l >= 0) bin[l * N + lbase[l] + pos] = n;
}

// ---- K2: out = X ----
__global__ void copy_kernel(const float4* __restrict__ src, float4* __restrict__ dst, int n4) {
    int i = blockIdx.x * blockDim.x + threadIdx.x;
    int stride = gridDim.x * blockDim.x;
    for (; i < n4; i += stride) dst[i] = src[i];
}

// ---- K3: Y[n] = bf16( 0.2*(X[n] @ W[l].T + b[l]) ) for binned nodes ----
__global__ __launch_bounds__(256) void transform_kernel(
    const float* __restrict__ X, const float* __restrict__ Wg,
    const float* __restrict__ bg, const int* __restrict__ cnt,
    const int* __restrict__ bin, u16* __restrict__ Y, int N, int blocksPerLevel)
{
    // Wt[j][f] = bf16(W[l][f][j]); row stride 136 u16 = 272B (16B-aligned, breaks pow2 banks)
    __shared__ __align__(16) u16 Wt[FDIM][136];
    // Xt[j][n] = bf16(X[node_n][j]); row stride 68 u16 = 136B (8B-aligned)
    __shared__ __align__(16) u16 Xt[FDIM][NT + 4];
    __shared__ int nodes_s[NT];

    int l     = blockIdx.x / blocksPerLevel;
    int chunk = blockIdx.x % blocksPerLevel;
    int m_total = cnt[l];
    int base = chunk * NT;
    if (base >= m_total) return;
    int m = min(NT, m_total - base);
    int t = threadIdx.x;

    if (t < NT) nodes_s[t] = (t < m) ? bin[l * N + base + t] : -1;
    __syncthreads();

    // stage W[l] transposed: 16384 elems, 64 per thread, coalesced global reads
    const float* Wl = Wg + l * FDIM * FDIM;
    #pragma unroll
    for (int k = 0; k < (FDIM * FDIM) / 256; ++k) {
        int flat = t + k * 256;
        int f = flat >> 7, j = flat & 127;
        Wt[j][f] = f2bf(Wl[flat]);
    }
    // stage X tile transposed: NT*128 elems, 32 per thread
    #pragma unroll
    for (int k = 0; k < (NT * FDIM) / 256; ++k) {
        int flat = t + k * 256;
        int nl = flat >> 7, j = flat & 127;
        int node = nodes_s[nl];
        float v = (node >= 0) ? X[node * FDIM + j] : 0.0f;
        Xt[j][nl] = f2bf(v);
    }
    __syncthreads();

    int ng = t >> 4;          // 0..15 -> nodes n0..n0+3
    int fg = t & 15;          // 0..15 -> feats f0..f0+7
    int n0 = ng * 4, f0 = fg * 8;

    float acc[4][8];
    #pragma unroll
    for (int a = 0; a < 4; ++a)
        #pragma unroll
        for (int c = 0; c < 8; ++c) acc[a][c] = 0.0f;

    for (int j = 0; j < FDIM; ++j) {
        uint2 xp = *(const uint2*)&Xt[j][n0];   // 4 bf16 (broadcast-heavy, conflict-free)
        uint4 wp = *(const uint4*)&Wt[j][f0];   // 8 bf16, 256B contiguous across lanes
        float xv[4] = { bf_lo(xp.x), bf_hi(xp.x), bf_lo(xp.y), bf_hi(xp.y) };
        float wv[8] = { bf_lo(wp.x), bf_hi(wp.x), bf_lo(wp.y), bf_hi(wp.y),
                        bf_lo(wp.z), bf_hi(wp.z), bf_lo(wp.w), bf_hi(wp.w) };
        #pragma unroll
        for (int a = 0; a < 4; ++a)
            #pragma unroll
            for (int c = 0; c < 8; ++c)
                acc[a][c] = fmaf(xv[a], wv[c], acc[a][c]);
    }

    const float* bl = bg + l * FDIM;
    float bv[8];
    #pragma unroll
    for (int c = 0; c < 8; ++c) bv[c] = bl[f0 + c];

    #pragma unroll
    for (int a = 0; a < 4; ++a) {
        int node = nodes_s[n0 + a];
        if (node < 0) continue;
        u32 pk[4];
        #pragma unroll
        for (int c = 0; c < 4; ++c) {
            u16 e0 = f2bf(0.2f * (acc[a][2 * c]     + bv[2 * c]));
            u16 e1 = f2bf(0.2f * (acc[a][2 * c + 1] + bv[2 * c + 1]));
            pk[c] = (u32)e0 | ((u32)e1 << 16);
        }
        uint4 v = make_uint4(pk[0], pk[1], pk[2], pk[3]);
        *(uint4*)&Y[node * FDIM + f0] = v;   // 16B store, aligned
    }
}

// ---- K4: for each edge, if lv[hi] > lv[lo]: out[hi] += Y[lo] (atomic) ----
__global__ __launch_bounds__(256) void scatter_kernel(
    const int* __restrict__ edges, const int* __restrict__ lv,
    const u32* __restrict__ Y2, float* __restrict__ out, int E)
{
    int gid = blockIdx.x * blockDim.x + threadIdx.x;
    int e = gid >> 6;
    int lane = gid & 63;
    if (e >= E) return;
    int lo = edges[2 * e];
    int hi = edges[2 * e + 1];
    int ll = lv[lo];
    int hl = lv[hi];
    if (hl <= ll) return;   // valid <=> lv[hi] > lv[lo] (implies ll < 4)
    u32 p = Y2[lo * (FDIM / 2) + lane];       // 2 bf16, already scaled by 0.2
    float v0 = bf_lo(p);
    float v1 = bf_hi(p);
    float* dst = out + hi * FDIM + lane * 2;
    atomicAdd(dst, v0);
    atomicAdd(dst + 1, v1);
}

extern "C" void kernel_launch(void* const* d_in, const int* in_sizes, int n_in,
                              void* d_out, int out_size, void* d_ws, size_t ws_size,
                              hipStream_t stream) {
    const float* X  = (const float*)d_in[0];
    const float* Wg = (const float*)d_in[1];
    const float* bg = (const float*)d_in[2];
    const int*   lv = (const int*)d_in[3];
    const int*   eg = (const int*)d_in[4];
    float* out = (float*)d_out;

    int N = in_sizes[3];
    int E = in_sizes[4] / 2;

    // workspace layout: Y (bf16, N*F) | cnt (8 ints) | bin (4*N ints)
    u16* Y   = (u16*)d_ws;
    char* p  = (char*)d_ws + (size_t)N * FDIM * sizeof(u16);
    int* cnt = (int*)p;
    int* bin = (int*)(p + 32);

    hipMemsetAsync(cnt, 0, 8 * sizeof(int), stream);

    bin_kernel<<<(N + 255) / 256, 256, 0, stream>>>(lv, cnt, bin, N);

    int n4 = (N * FDIM) / 4;
    copy_kernel<<<2048, 256, 0, stream>>>((const float4*)X, (float4*)out, n4);

    int blocksPerLevel = (N + NT - 1) / NT;
    transform_kernel<<<NLEV * blocksPerLevel, 256, 0, stream>>>(
        X, Wg, bg, cnt, bin, Y, N, blocksPerLevel);

    int totalThreads = E * 64;
    scatter_kernel<<<(totalThreads + 255) / 256, 256, 0, stream>>>(
        eg, lv, (const u32*)Y, out, E);
}

// Round 3
// 148.439 us; speedup vs baseline: 4.6805x; 1.8032x over previous
//
#include <hip/hip_runtime.h>
#include <hip/hip_bf16.h>

#define FDIM 128
#define NLEV 4
#define NT   64   // nodes per transform block

typedef unsigned int  u32;
typedef unsigned short u16;

__device__ __forceinline__ float bf_lo(u32 p) { return __uint_as_float(p << 16); }
__device__ __forceinline__ float bf_hi(u32 p) { return __uint_as_float(p & 0xffff0000u); }
__device__ __forceinline__ u16 f2bf(float f) {
    u32 u = __float_as_uint(f);
    u32 r = (u + 0x7fffu + ((u >> 16) & 1u)) >> 16;   // round-nearest-even
    return (u16)r;
}

// ---- K1: bin nodes by level (for transform). LDS histogram -> 4 global atomics/block ----
__global__ __launch_bounds__(256) void bin_kernel(const int* __restrict__ lv,
                                                  int* __restrict__ cnt,
                                                  int* __restrict__ bin, int N) {
    __shared__ int lcnt[NLEV];
    __shared__ int lbase[NLEV];
    int t = threadIdx.x;
    if (t < NLEV) lcnt[t] = 0;
    __syncthreads();
    int n = blockIdx.x * blockDim.x + t;
    int l = -1, pos = 0;
    if (n < N) {
        l = lv[n];
        if (l >= 0 && l < NLEV) pos = atomicAdd(&lcnt[l], 1);
        else l = -1;
    }
    __syncthreads();
    if (t < NLEV) lbase[t] = lcnt[t] ? atomicAdd(&cnt[t], lcnt[t]) : 0;
    __syncthreads();
    if (l >= 0) bin[l * N + lbase[l] + pos] = n;
}

// ---- K2: deg[hi]++ for valid edges (100k counters -> low contention) ----
__global__ __launch_bounds__(256) void hist_kernel(const int* __restrict__ edges,
                                                   const int* __restrict__ lv,
                                                   int* __restrict__ deg, int E) {
    int e = blockIdx.x * 256 + threadIdx.x;
    if (e >= E) return;
    int lo = edges[2 * e];
    int hi = edges[2 * e + 1];
    if (lv[hi] > lv[lo]) atomicAdd(&deg[hi], 1);   // valid <=> lv[hi] > lv[lo]
}

// ---- K3a: per-1024-chunk local exclusive scan + chunk totals ----
__global__ __launch_bounds__(256) void scan_local(const int* __restrict__ deg,
                                                  int* __restrict__ rowstart,
                                                  int* __restrict__ bsum, int N) {
    __shared__ int part[256];
    int t = threadIdx.x;
    int base = blockIdx.x * 1024 + t * 4;
    int v[4];
    #pragma unroll
    for (int k = 0; k < 4; ++k) v[k] = (base + k < N) ? deg[base + k] : 0;
    int s = v[0] + v[1] + v[2] + v[3];
    part[t] = s;
    __syncthreads();
    for (int off = 1; off < 256; off <<= 1) {      // Hillis-Steele inclusive
        int x = (t >= off) ? part[t - off] : 0;
        __syncthreads();
        part[t] += x;
        __syncthreads();
    }
    if (t == 255) bsum[blockIdx.x] = part[255];
    int run = part[t] - s;                         // exclusive prefix of my chunk
    #pragma unroll
    for (int k = 0; k < 4; ++k) {
        if (base + k < N) rowstart[base + k] = run;
        run += v[k];
    }
}

// ---- K3b: exclusive scan of chunk totals (nb <= 128) ----
__global__ __launch_bounds__(128) void scan_blocks(int* __restrict__ bsum, int nb) {
    __shared__ int s[128];
    int t = threadIdx.x;
    s[t] = (t < nb) ? bsum[t] : 0;
    __syncthreads();
    if (t == 0) {
        int run = 0;
        for (int i = 0; i < nb; ++i) { int v = s[i]; s[i] = run; run += v; }
    }
    __syncthreads();
    if (t < nb) bsum[t] = s[t];
}

// ---- K3c: add chunk offsets ----
__global__ __launch_bounds__(256) void scan_add(int* __restrict__ rowstart,
                                                const int* __restrict__ bsum, int N) {
    int i = blockIdx.x * 256 + threadIdx.x;
    if (i < N) rowstart[i] += bsum[i >> 10];
}

// ---- K4: csr[rowstart[hi] + ncur[hi]++] = lo for valid edges ----
__global__ __launch_bounds__(256) void fill_kernel(const int* __restrict__ edges,
                                                   const int* __restrict__ lv,
                                                   const int* __restrict__ rowstart,
                                                   int* __restrict__ ncur,
                                                   int* __restrict__ csr, int E) {
    int e = blockIdx.x * 256 + threadIdx.x;
    if (e >= E) return;
    int lo = edges[2 * e];
    int hi = edges[2 * e + 1];
    if (lv[hi] > lv[lo]) {
        int s = rowstart[hi] + atomicAdd(&ncur[hi], 1);
        csr[s] = lo;
    }
}

// ---- K5: Y[n] = bf16( 0.2*(X[n] @ W[l].T + b[l]) ) for binned nodes ----
__global__ __launch_bounds__(256) void transform_kernel(
    const float* __restrict__ X, const float* __restrict__ Wg,
    const float* __restrict__ bg, const int* __restrict__ cnt,
    const int* __restrict__ bin, u16* __restrict__ Y, int N, int blocksPerLevel)
{
    __shared__ __align__(16) u16 Wt[FDIM][136];
    __shared__ __align__(16) u16 Xt[FDIM][NT + 4];
    __shared__ int nodes_s[NT];

    int l     = blockIdx.x / blocksPerLevel;
    int chunk = blockIdx.x % blocksPerLevel;
    int m_total = cnt[l];
    int base = chunk * NT;
    if (base >= m_total) return;
    int m = min(NT, m_total - base);
    int t = threadIdx.x;

    if (t < NT) nodes_s[t] = (t < m) ? bin[l * N + base + t] : -1;
    __syncthreads();

    const float* Wl = Wg + l * FDIM * FDIM;
    #pragma unroll
    for (int k = 0; k < (FDIM * FDIM) / 256; ++k) {
        int flat = t + k * 256;
        int f = flat >> 7, j = flat & 127;
        Wt[j][f] = f2bf(Wl[flat]);
    }
    #pragma unroll
    for (int k = 0; k < (NT * FDIM) / 256; ++k) {
        int flat = t + k * 256;
        int nl = flat >> 7, j = flat & 127;
        int node = nodes_s[nl];
        float v = (node >= 0) ? X[node * FDIM + j] : 0.0f;
        Xt[j][nl] = f2bf(v);
    }
    __syncthreads();

    int ng = t >> 4, fg = t & 15;
    int n0 = ng * 4, f0 = fg * 8;

    float acc[4][8];
    #pragma unroll
    for (int a = 0; a < 4; ++a)
        #pragma unroll
        for (int c = 0; c < 8; ++c) acc[a][c] = 0.0f;

    for (int j = 0; j < FDIM; ++j) {
        uint2 xp = *(const uint2*)&Xt[j][n0];
        uint4 wp = *(const uint4*)&Wt[j][f0];
        float xv[4] = { bf_lo(xp.x), bf_hi(xp.x), bf_lo(xp.y), bf_hi(xp.y) };
        float wv[8] = { bf_lo(wp.x), bf_hi(wp.x), bf_lo(wp.y), bf_hi(wp.y),
                        bf_lo(wp.z), bf_hi(wp.z), bf_lo(wp.w), bf_hi(wp.w) };
        #pragma unroll
        for (int a = 0; a < 4; ++a)
            #pragma unroll
            for (int c = 0; c < 8; ++c)
                acc[a][c] = fmaf(xv[a], wv[c], acc[a][c]);
    }

    const float* bl = bg + l * FDIM;
    float bv[8];
    #pragma unroll
    for (int c = 0; c < 8; ++c) bv[c] = bl[f0 + c];

    #pragma unroll
    for (int a = 0; a < 4; ++a) {
        int node = nodes_s[n0 + a];
        if (node < 0) continue;
        u32 pk[4];
        #pragma unroll
        for (int c = 0; c < 4; ++c) {
            u16 e0 = f2bf(0.2f * (acc[a][2 * c]     + bv[2 * c]));
            u16 e1 = f2bf(0.2f * (acc[a][2 * c + 1] + bv[2 * c + 1]));
            pk[c] = (u32)e0 | ((u32)e1 << 16);
        }
        uint4 v = make_uint4(pk[0], pk[1], pk[2], pk[3]);
        *(uint4*)&Y[node * FDIM + f0] = v;
    }
}

// ---- K6: gather. One wave per node: out[hi] = X[hi] + sum_{lo in csr row} Y[lo] ----
__global__ __launch_bounds__(256) void gather_kernel(
    const float* __restrict__ X, const u32* __restrict__ Y2,
    const int* __restrict__ rowstart, const int* __restrict__ deg,
    const int* __restrict__ csr, float* __restrict__ out, int N)
{
    int node = blockIdx.x * 4 + (threadIdx.x >> 6);
    int lane = threadIdx.x & 63;
    if (node >= N) return;
    int row = rowstart[node];
    int d   = deg[node];
    float a0 = 0.0f, a1 = 0.0f;
    for (int base = 0; base < d; base += 64) {
        int c = min(64, d - base);
        int myLo = (lane < c) ? csr[row + base + lane] : 0;
        for (int i = 0; i < c; ++i) {
            int lo = __shfl(myLo, i, 64);
            u32 p = Y2[lo * (FDIM / 2) + lane];   // 256B coalesced per edge
            a0 += bf_lo(p);
            a1 += bf_hi(p);
        }
    }
    float2 xv = *(const float2*)&X[(size_t)node * FDIM + lane * 2];
    float2 o; o.x = xv.x + a0; o.y = xv.y + a1;
    *(float2*)&out[(size_t)node * FDIM + lane * 2] = o;
}

extern "C" void kernel_launch(void* const* d_in, const int* in_sizes, int n_in,
                              void* d_out, int out_size, void* d_ws, size_t ws_size,
                              hipStream_t stream) {
    const float* X  = (const float*)d_in[0];
    const float* Wg = (const float*)d_in[1];
    const float* bg = (const float*)d_in[2];
    const int*   lv = (const int*)d_in[3];
    const int*   eg = (const int*)d_in[4];
    float* out = (float*)d_out;

    int N = in_sizes[3];
    int E = in_sizes[4] / 2;

    // workspace layout:
    //   Y (bf16, N*F) | cnt(8) deg(N) ncur(N)  [zeroed together] | rowstart(N) | bsum(128) | bin(4N) | csr(E)
    char* p = (char*)d_ws;
    u16* Y        = (u16*)p;            p += (size_t)N * FDIM * sizeof(u16);
    int* cnt      = (int*)p;            p += 8 * sizeof(int);
    int* deg      = (int*)p;            p += (size_t)N * sizeof(int);
    int* ncur     = (int*)p;            p += (size_t)N * sizeof(int);
    int* rowstart = (int*)p;            p += (size_t)N * sizeof(int);
    int* bsum     = (int*)p;            p += 128 * sizeof(int);
    int* bin      = (int*)p;            p += (size_t)4 * N * sizeof(int);
    int* csr      = (int*)p;

    // zero cnt+deg+ncur in one shot
    hipMemsetAsync(cnt, 0, (size_t)(2 * N + 8) * sizeof(int), stream);

    bin_kernel<<<(N + 255) / 256, 256, 0, stream>>>(lv, cnt, bin, N);
    hist_kernel<<<(E + 255) / 256, 256, 0, stream>>>(eg, lv, deg, E);

    int nb = (N + 1023) / 1024;   // <= 128 for N <= 131072
    scan_local<<<nb, 256, 0, stream>>>(deg, rowstart, bsum, N);
    scan_blocks<<<1, 128, 0, stream>>>(bsum, nb);
    scan_add<<<(N + 255) / 256, 256, 0, stream>>>(rowstart, bsum, N);

    fill_kernel<<<(E + 255) / 256, 256, 0, stream>>>(eg, lv, rowstart, ncur, csr, E);

    int blocksPerLevel = (N + NT - 1) / NT;
    transform_kernel<<<NLEV * blocksPerLevel, 256, 0, stream>>>(
        X, Wg, bg, cnt, bin, Y, N, blocksPerLevel);

    gather_kernel<<<(N + 3) / 4, 256, 0, stream>>>(
        X, (const u32*)Y, rowstart, deg, csr, out, N);
}

// Round 4
// 106.091 us; speedup vs baseline: 6.5488x; 1.3992x over previous
//
#include <hip/hip_runtime.h>
#include <hip/hip_bf16.h>

#define FDIM 128
#define NLEV 4
#define NT   64   // nodes per transform block
#define WPAD 136  // padded row stride (u16) for LDS tiles: 272B -> 2-way bank alias (free)

typedef unsigned int  u32;
typedef unsigned short u16;

typedef __attribute__((ext_vector_type(8))) short short8v;  // 8 bf16 (4 VGPRs)
typedef __attribute__((ext_vector_type(4))) float f32x4;

__device__ __forceinline__ float bf_lo(u32 p) { return __uint_as_float(p << 16); }
__device__ __forceinline__ float bf_hi(u32 p) { return __uint_as_float(p & 0xffff0000u); }
__device__ __forceinline__ u16 f2bf(float f) {
    u32 u = __float_as_uint(f);
    u32 r = (u + 0x7fffu + ((u >> 16) & 1u)) >> 16;   // round-nearest-even
    return (u16)r;
}
__device__ __forceinline__ u32 pack2(float a, float b) {
    return (u32)f2bf(a) | ((u32)f2bf(b) << 16);
}

// ---- K1: bin nodes by level. LDS histogram -> 4 global atomics/block ----
__global__ __launch_bounds__(256) void bin_kernel(const int* __restrict__ lv,
                                                  int* __restrict__ cnt,
                                                  int* __restrict__ bin, int N) {
    __shared__ int lcnt[NLEV];
    __shared__ int lbase[NLEV];
    int t = threadIdx.x;
    if (t < NLEV) lcnt[t] = 0;
    __syncthreads();
    int n = blockIdx.x * blockDim.x + t;
    int l = -1, pos = 0;
    if (n < N) {
        l = lv[n];
        if (l >= 0 && l < NLEV) pos = atomicAdd(&lcnt[l], 1);
        else l = -1;
    }
    __syncthreads();
    if (t < NLEV) lbase[t] = lcnt[t] ? atomicAdd(&cnt[t], lcnt[t]) : 0;
    __syncthreads();
    if (l >= 0) bin[l * N + lbase[l] + pos] = n;
}

// ---- K2: deg[hi]++ for valid edges ----
__global__ __launch_bounds__(256) void hist_kernel(const int* __restrict__ edges,
                                                   const int* __restrict__ lv,
                                                   int* __restrict__ deg, int E) {
    int e = blockIdx.x * 256 + threadIdx.x;
    if (e >= E) return;
    int lo = edges[2 * e];
    int hi = edges[2 * e + 1];
    if (lv[hi] > lv[lo]) atomicAdd(&deg[hi], 1);   // valid <=> lv[hi] > lv[lo]
}

// ---- K3a: per-1024-chunk local exclusive scan + chunk totals ----
__global__ __launch_bounds__(256) void scan_local(const int* __restrict__ deg,
                                                  int* __restrict__ rowstart,
                                                  int* __restrict__ bsum, int N) {
    __shared__ int part[256];
    int t = threadIdx.x;
    int base = blockIdx.x * 1024 + t * 4;
    int v[4];
    #pragma unroll
    for (int k = 0; k < 4; ++k) v[k] = (base + k < N) ? deg[base + k] : 0;
    int s = v[0] + v[1] + v[2] + v[3];
    part[t] = s;
    __syncthreads();
    for (int off = 1; off < 256; off <<= 1) {      // Hillis-Steele inclusive
        int x = (t >= off) ? part[t - off] : 0;
        __syncthreads();
        part[t] += x;
        __syncthreads();
    }
    if (t == 255) bsum[blockIdx.x] = part[255];
    int run = part[t] - s;
    #pragma unroll
    for (int k = 0; k < 4; ++k) {
        if (base + k < N) rowstart[base + k] = run;
        run += v[k];
    }
}

// ---- K3b: exclusive scan of chunk totals (nb <= 128) ----
__global__ __launch_bounds__(128) void scan_blocks(int* __restrict__ bsum, int nb) {
    __shared__ int s[128];
    int t = threadIdx.x;
    s[t] = (t < nb) ? bsum[t] : 0;
    __syncthreads();
    if (t == 0) {
        int run = 0;
        for (int i = 0; i < nb; ++i) { int v = s[i]; s[i] = run; run += v; }
    }
    __syncthreads();
    if (t < nb) bsum[t] = s[t];
}

// ---- K3c: add chunk offsets ----
__global__ __launch_bounds__(256) void scan_add(int* __restrict__ rowstart,
                                                const int* __restrict__ bsum, int N) {
    int i = blockIdx.x * 256 + threadIdx.x;
    if (i < N) rowstart[i] += bsum[i >> 10];
}

// ---- K4: csr[rowstart[hi] + ncur[hi]++] = lo for valid edges ----
__global__ __launch_bounds__(256) void fill_kernel(const int* __restrict__ edges,
                                                   const int* __restrict__ lv,
                                                   const int* __restrict__ rowstart,
                                                   int* __restrict__ ncur,
                                                   int* __restrict__ csr, int E) {
    int e = blockIdx.x * 256 + threadIdx.x;
    if (e >= E) return;
    int lo = edges[2 * e];
    int hi = edges[2 * e + 1];
    if (lv[hi] > lv[lo]) {
        int s = rowstart[hi] + atomicAdd(&ncur[hi], 1);
        csr[s] = lo;
    }
}

// ---- K5 (MFMA): Y[n] = bf16( 0.2*(X[n] @ W[l].T + b[l]) ) for binned nodes ----
// Per block: 4 waves, each computes a 16-node x 128-feat tile via mfma_f32_16x16x32_bf16.
// A = X tile (nodes x K), B[k][f] = W[f][k]  (W row-major IS the B^T layout MFMA wants).
__global__ __launch_bounds__(256) void transform_kernel(
    const float* __restrict__ X, const float* __restrict__ Wg,
    const float* __restrict__ bg, const int* __restrict__ cnt,
    const int* __restrict__ bin, u16* __restrict__ Y, int N, int blocksPerLevel)
{
    __shared__ __align__(16) u16 Wt[FDIM][WPAD];  // W[l] bf16 row-major, padded
    __shared__ __align__(16) u16 Xt[NT][WPAD];    // X tile bf16 row-major; reused for Y out
    __shared__ int nodes_s[NT];

    int l     = blockIdx.x / blocksPerLevel;
    int chunk = blockIdx.x % blocksPerLevel;
    int m_total = cnt[l];
    int base = chunk * NT;
    if (base >= m_total) return;
    int m = min(NT, m_total - base);
    int t = threadIdx.x;

    if (t < NT) nodes_s[t] = (t < m) ? bin[l * N + base + t] : -1;
    __syncthreads();

    // stage W[l]: 16384 floats = 4096 float4; 256 threads x 16
    const float4* Wl4 = (const float4*)(Wg + (size_t)l * FDIM * FDIM);
    #pragma unroll
    for (int k = 0; k < 16; ++k) {
        int flat4 = t + k * 256;
        int row = flat4 >> 5;        // 32 float4 per row
        int c4  = flat4 & 31;
        float4 v = Wl4[flat4];
        *(uint2*)&Wt[row][c4 * 4] = make_uint2(pack2(v.x, v.y), pack2(v.z, v.w));
    }
    // stage X tile: 64 rows x 128 = 2048 float4; 256 threads x 8
    #pragma unroll
    for (int k = 0; k < 8; ++k) {
        int flat4 = t + k * 256;
        int row = flat4 >> 5;
        int c4  = flat4 & 31;
        int node = nodes_s[row];
        float4 v = (node >= 0) ? ((const float4*)(X + (size_t)node * FDIM))[c4]
                               : make_float4(0.f, 0.f, 0.f, 0.f);
        *(uint2*)&Xt[row][c4 * 4] = make_uint2(pack2(v.x, v.y), pack2(v.z, v.w));
    }
    __syncthreads();

    int wid  = t >> 6;        // wave 0..3 -> node rows wid*16..+15
    int lane = t & 63;
    int arow = lane & 15;     // A row / B col / D col within 16
    int kgrp = lane >> 4;     // k sub-group: k = kgrp*8 + i

    f32x4 acc[8];
    #pragma unroll
    for (int ft = 0; ft < 8; ++ft) acc[ft] = (f32x4){0.f, 0.f, 0.f, 0.f};

    #pragma unroll
    for (int kstep = 0; kstep < 4; ++kstep) {
        int k0 = kstep * 32 + kgrp * 8;
        short8v a = *(const short8v*)&Xt[wid * 16 + arow][k0];
        #pragma unroll
        for (int ft = 0; ft < 8; ++ft) {
            short8v b = *(const short8v*)&Wt[ft * 16 + arow][k0];
            acc[ft] = __builtin_amdgcn_mfma_f32_16x16x32_bf16(a, b, acc[ft], 0, 0, 0);
        }
    }

    // epilogue: y = bf16(0.2*(acc + bias)); D layout: col = ft*16+arow, row = kgrp*4+reg
    const float* bl = bg + l * FDIM;
    #pragma unroll
    for (int ft = 0; ft < 8; ++ft) {
        float bv = bl[ft * 16 + arow];
        #pragma unroll
        for (int reg = 0; reg < 4; ++reg) {
            int r = wid * 16 + kgrp * 4 + reg;          // this wave's own rows only
            Xt[r][ft * 16 + arow] = f2bf(0.2f * (acc[ft][reg] + bv));
        }
    }
    __syncthreads();

    // coalesced copy-out: 64 rows x 256B; 256 threads x 4 x 16B
    #pragma unroll
    for (int k = 0; k < 4; ++k) {
        int flat16 = t + k * 256;
        int row = flat16 >> 4;       // 16 uint4 per row
        int c   = flat16 & 15;
        int node = nodes_s[row];
        if (node >= 0)
            *(uint4*)&Y[(size_t)node * FDIM + c * 8] = *(const uint4*)&Xt[row][c * 8];
    }
}

// ---- K6: gather. One wave per node: out[hi] = X[hi] + sum_{lo in csr row} Y[lo] ----
__global__ __launch_bounds__(256) void gather_kernel(
    const float* __restrict__ X, const u32* __restrict__ Y2,
    const int* __restrict__ rowstart, const int* __restrict__ deg,
    const int* __restrict__ csr, float* __restrict__ out, int N)
{
    int node = blockIdx.x * 4 + (threadIdx.x >> 6);
    int lane = threadIdx.x & 63;
    if (node >= N) return;
    int row = rowstart[node];
    int d   = deg[node];
    float a0 = 0.0f, a1 = 0.0f;
    for (int base = 0; base < d; base += 64) {
        int c = min(64, d - base);
        int myLo = (lane < c) ? csr[row + base + lane] : 0;
        for (int i = 0; i < c; ++i) {
            int lo = __shfl(myLo, i, 64);
            u32 p = Y2[lo * (FDIM / 2) + lane];   // 256B coalesced per edge
            a0 += bf_lo(p);
            a1 += bf_hi(p);
        }
    }
    float2 xv = *(const float2*)&X[(size_t)node * FDIM + lane * 2];
    float2 o; o.x = xv.x + a0; o.y = xv.y + a1;
    *(float2*)&out[(size_t)node * FDIM + lane * 2] = o;
}

extern "C" void kernel_launch(void* const* d_in, const int* in_sizes, int n_in,
                              void* d_out, int out_size, void* d_ws, size_t ws_size,
                              hipStream_t stream) {
    const float* X  = (const float*)d_in[0];
    const float* Wg = (const float*)d_in[1];
    const float* bg = (const float*)d_in[2];
    const int*   lv = (const int*)d_in[3];
    const int*   eg = (const int*)d_in[4];
    float* out = (float*)d_out;

    int N = in_sizes[3];
    int E = in_sizes[4] / 2;

    // workspace: Y (bf16 N*F) | cnt(8) deg(N) ncur(N) [zeroed together] | rowstart(N) | bsum(128) | bin(4N) | csr(E)
    char* p = (char*)d_ws;
    u16* Y        = (u16*)p;            p += (size_t)N * FDIM * sizeof(u16);
    int* cnt      = (int*)p;            p += 8 * sizeof(int);
    int* deg      = (int*)p;            p += (size_t)N * sizeof(int);
    int* ncur     = (int*)p;            p += (size_t)N * sizeof(int);
    int* rowstart = (int*)p;            p += (size_t)N * sizeof(int);
    int* bsum     = (int*)p;            p += 128 * sizeof(int);
    int* bin      = (int*)p;            p += (size_t)4 * N * sizeof(int);
    int* csr      = (int*)p;

    hipMemsetAsync(cnt, 0, (size_t)(2 * N + 8) * sizeof(int), stream);

    bin_kernel<<<(N + 255) / 256, 256, 0, stream>>>(lv, cnt, bin, N);
    hist_kernel<<<(E + 255) / 256, 256, 0, stream>>>(eg, lv, deg, E);

    int nb = (N + 1023) / 1024;   // <= 128 for N <= 131072
    scan_local<<<nb, 256, 0, stream>>>(deg, rowstart, bsum, N);
    scan_blocks<<<1, 128, 0, stream>>>(bsum, nb);
    scan_add<<<(N + 255) / 256, 256, 0, stream>>>(rowstart, bsum, N);

    fill_kernel<<<(E + 255) / 256, 256, 0, stream>>>(eg, lv, rowstart, ncur, csr, E);

    int blocksPerLevel = (N + NT - 1) / NT;
    transform_kernel<<<NLEV * blocksPerLevel, 256, 0, stream>>>(
        X, Wg, bg, cnt, bin, Y, N, blocksPerLevel);

    gather_kernel<<<(N + 3) / 4, 256, 0, stream>>>(
        X, (const u32*)Y, rowstart, deg, csr, out, N);
}

// Round 5
// 89.164 us; speedup vs baseline: 7.7921x; 1.1898x over previous
//
#include <hip/hip_runtime.h>
#include <hip/hip_bf16.h>

#define FDIM 128
#define NLEV 4
#define NT   64   // nodes per transform block
#define WPAD 136  // padded row stride (u16) for LDS tiles: 272B -> 2-way bank alias (free)

typedef unsigned int  u32;
typedef unsigned short u16;

typedef __attribute__((ext_vector_type(8))) short short8v;  // 8 bf16 (4 VGPRs)
typedef __attribute__((ext_vector_type(4))) float f32x4;

__device__ __forceinline__ float bf_lo(u32 p) { return __uint_as_float(p << 16); }
__device__ __forceinline__ float bf_hi(u32 p) { return __uint_as_float(p & 0xffff0000u); }
__device__ __forceinline__ u16 f2bf(float f) {
    u32 u = __float_as_uint(f);
    u32 r = (u + 0x7fffu + ((u >> 16) & 1u)) >> 16;   // round-nearest-even
    return (u16)r;
}
__device__ __forceinline__ u32 pack2(float a, float b) {
    return (u32)f2bf(a) | ((u32)f2bf(b) << 16);
}

// ---- K1: fused node-binning (first nodeBlocks blocks) + edge histogram (all blocks) ----
__global__ __launch_bounds__(256) void binhist_kernel(
    const int* __restrict__ lv, int* __restrict__ cnt, int* __restrict__ bin,
    const int* __restrict__ edges, int* __restrict__ deg,
    int N, int E, int nodeBlocks)
{
    int t = threadIdx.x;
    int b = blockIdx.x;

    // edge part: deg[hi]++ for valid edges (valid <=> lv[hi] > lv[lo])
    int e = b * 256 + t;
    if (e < E) {
        int lo = edges[2 * e];
        int hi = edges[2 * e + 1];
        if (lv[hi] > lv[lo]) atomicAdd(&deg[hi], 1);
    }

    // node part: bin by level, LDS histogram -> 4 global atomics/block
    if (b < nodeBlocks) {
        __shared__ int lcnt[NLEV];
        __shared__ int lbase[NLEV];
        if (t < NLEV) lcnt[t] = 0;
        __syncthreads();
        int n = b * 256 + t;
        int l = -1, pos = 0;
        if (n < N) {
            l = lv[n];
            if (l >= 0 && l < NLEV) pos = atomicAdd(&lcnt[l], 1);
            else l = -1;
        }
        __syncthreads();
        if (t < NLEV) lbase[t] = lcnt[t] ? atomicAdd(&cnt[t], lcnt[t]) : 0;
        __syncthreads();
        if (l >= 0) bin[l * N + lbase[l] + pos] = n;
    }
}

// ---- K2a: per-1024-chunk local exclusive scan + chunk totals ----
__global__ __launch_bounds__(256) void scan_local(const int* __restrict__ deg,
                                                  int* __restrict__ rowstart,
                                                  int* __restrict__ bsum, int N) {
    __shared__ int part[256];
    int t = threadIdx.x;
    int base = blockIdx.x * 1024 + t * 4;
    int v[4];
    #pragma unroll
    for (int k = 0; k < 4; ++k) v[k] = (base + k < N) ? deg[base + k] : 0;
    int s = v[0] + v[1] + v[2] + v[3];
    part[t] = s;
    __syncthreads();
    for (int off = 1; off < 256; off <<= 1) {      // Hillis-Steele inclusive
        int x = (t >= off) ? part[t - off] : 0;
        __syncthreads();
        part[t] += x;
        __syncthreads();
    }
    if (t == 255) bsum[blockIdx.x] = part[255];
    int run = part[t] - s;
    #pragma unroll
    for (int k = 0; k < 4; ++k) {
        if (base + k < N) rowstart[base + k] = run;
        run += v[k];
    }
}

// ---- K2b: exclusive scan of chunk totals (nb <= 128) ----
__global__ __launch_bounds__(128) void scan_blocks(int* __restrict__ bsum, int nb) {
    __shared__ int s[128];
    int t = threadIdx.x;
    s[t] = (t < nb) ? bsum[t] : 0;
    __syncthreads();
    if (t == 0) {
        int run = 0;
        for (int i = 0; i < nb; ++i) { int v = s[i]; s[i] = run; run += v; }
    }
    __syncthreads();
    if (t < nb) bsum[t] = s[t];
}

// ---- K3: csr[rs(hi) + ncur[hi]++] = lo for valid edges (bsum folded) ----
__global__ __launch_bounds__(256) void fill_kernel(const int* __restrict__ edges,
                                                   const int* __restrict__ lv,
                                                   const int* __restrict__ rowstart,
                                                   const int* __restrict__ bsum,
                                                   int* __restrict__ ncur,
                                                   int* __restrict__ csr, int E) {
    int e = blockIdx.x * 256 + threadIdx.x;
    if (e >= E) return;
    int lo = edges[2 * e];
    int hi = edges[2 * e + 1];
    if (lv[hi] > lv[lo]) {
        int s = rowstart[hi] + bsum[hi >> 10] + atomicAdd(&ncur[hi], 1);
        csr[s] = lo;
    }
}

// ---- K4 (MFMA): Y[n] = bf16( 0.2*(X[n] @ W[l].T + b[l]) ) for binned nodes ----
__global__ __launch_bounds__(256) void transform_kernel(
    const float* __restrict__ X, const float* __restrict__ Wg,
    const float* __restrict__ bg, const int* __restrict__ cnt,
    const int* __restrict__ bin, u16* __restrict__ Y, int N, int blocksPerLevel)
{
    __shared__ __align__(16) u16 Wt[FDIM][WPAD];  // W[l] bf16 row-major, padded
    __shared__ __align__(16) u16 Xt[NT][WPAD];    // X tile bf16 row-major; reused for Y out
    __shared__ int nodes_s[NT];

    int l     = blockIdx.x / blocksPerLevel;
    int chunk = blockIdx.x % blocksPerLevel;
    int m_total = cnt[l];
    int base = chunk * NT;
    if (base >= m_total) return;
    int m = min(NT, m_total - base);
    int t = threadIdx.x;

    if (t < NT) nodes_s[t] = (t < m) ? bin[l * N + base + t] : -1;
    __syncthreads();

    const float4* Wl4 = (const float4*)(Wg + (size_t)l * FDIM * FDIM);
    #pragma unroll
    for (int k = 0; k < 16; ++k) {
        int flat4 = t + k * 256;
        int row = flat4 >> 5;
        int c4  = flat4 & 31;
        float4 v = Wl4[flat4];
        *(uint2*)&Wt[row][c4 * 4] = make_uint2(pack2(v.x, v.y), pack2(v.z, v.w));
    }
    #pragma unroll
    for (int k = 0; k < 8; ++k) {
        int flat4 = t + k * 256;
        int row = flat4 >> 5;
        int c4  = flat4 & 31;
        int node = nodes_s[row];
        float4 v = (node >= 0) ? ((const float4*)(X + (size_t)node * FDIM))[c4]
                               : make_float4(0.f, 0.f, 0.f, 0.f);
        *(uint2*)&Xt[row][c4 * 4] = make_uint2(pack2(v.x, v.y), pack2(v.z, v.w));
    }
    __syncthreads();

    int wid  = t >> 6;
    int lane = t & 63;
    int arow = lane & 15;
    int kgrp = lane >> 4;

    f32x4 acc[8];
    #pragma unroll
    for (int ft = 0; ft < 8; ++ft) acc[ft] = (f32x4){0.f, 0.f, 0.f, 0.f};

    #pragma unroll
    for (int kstep = 0; kstep < 4; ++kstep) {
        int k0 = kstep * 32 + kgrp * 8;
        short8v a = *(const short8v*)&Xt[wid * 16 + arow][k0];
        #pragma unroll
        for (int ft = 0; ft < 8; ++ft) {
            short8v b = *(const short8v*)&Wt[ft * 16 + arow][k0];
            acc[ft] = __builtin_amdgcn_mfma_f32_16x16x32_bf16(a, b, acc[ft], 0, 0, 0);
        }
    }

    const float* bl = bg + l * FDIM;
    #pragma unroll
    for (int ft = 0; ft < 8; ++ft) {
        float bv = bl[ft * 16 + arow];
        #pragma unroll
        for (int reg = 0; reg < 4; ++reg) {
            int r = wid * 16 + kgrp * 4 + reg;
            Xt[r][ft * 16 + arow] = f2bf(0.2f * (acc[ft][reg] + bv));
        }
    }
    __syncthreads();

    #pragma unroll
    for (int k = 0; k < 4; ++k) {
        int flat16 = t + k * 256;
        int row = flat16 >> 4;
        int c   = flat16 & 15;
        int node = nodes_s[row];
        if (node >= 0)
            *(uint4*)&Y[(size_t)node * FDIM + c * 8] = *(const uint4*)&Xt[row][c * 8];
    }
}

// ---- K5: gather v2. Half-wave (32 lanes) per node; batch-4 Y loads for MLP ----
__global__ __launch_bounds__(256) void gather_kernel(
    const float* __restrict__ X, const uint2* __restrict__ Yp,
    const int* __restrict__ rowstart, const int* __restrict__ bsum,
    const int* __restrict__ deg, const int* __restrict__ csr,
    float* __restrict__ out, int N)
{
    int wid  = threadIdx.x >> 6;
    int lane = threadIdx.x & 63;
    int hl = lane >> 5;          // half: 0 or 1
    int sl = lane & 31;          // sub-lane within half
    int node = blockIdx.x * 8 + wid * 2 + hl;
    if (node >= N) return;

    // independent loads first: X row chunk, rowstart, bsum, deg
    float4 xv = *(const float4*)&X[(size_t)node * FDIM + sl * 4];
    int row = rowstart[node] + bsum[node >> 10];
    int d   = deg[node];

    float a0 = 0.f, a1 = 0.f, a2 = 0.f, a3 = 0.f;
    for (int base = 0; base < d; base += 32) {
        int c = min(32, d - base);
        int myLo = (sl < c) ? csr[row + base + sl] : 0;
        for (int i = 0; i < c; i += 4) {
            int b = min(4, c - i);
            uint2 p[4];
            #pragma unroll
            for (int j = 0; j < 4; ++j) {
                if (j < b) {
                    int lo = __shfl(myLo, hl * 32 + i + j, 64);
                    p[j] = Yp[(size_t)lo * (FDIM / 4) + sl];   // 8B/lane, 256B/edge
                }
            }
            #pragma unroll
            for (int j = 0; j < 4; ++j) {
                if (j < b) {
                    a0 += bf_lo(p[j].x); a1 += bf_hi(p[j].x);
                    a2 += bf_lo(p[j].y); a3 += bf_hi(p[j].y);
                }
            }
        }
    }
    float4 o = make_float4(xv.x + a0, xv.y + a1, xv.z + a2, xv.w + a3);
    *(float4*)&out[(size_t)node * FDIM + sl * 4] = o;
}

extern "C" void kernel_launch(void* const* d_in, const int* in_sizes, int n_in,
                              void* d_out, int out_size, void* d_ws, size_t ws_size,
                              hipStream_t stream) {
    const float* X  = (const float*)d_in[0];
    const float* Wg = (const float*)d_in[1];
    const float* bg = (const float*)d_in[2];
    const int*   lv = (const int*)d_in[3];
    const int*   eg = (const int*)d_in[4];
    float* out = (float*)d_out;

    int N = in_sizes[3];
    int E = in_sizes[4] / 2;

    // workspace: Y (bf16 N*F) | cnt(8) deg(N) ncur(N) [zeroed together] | rowstart(N) | bsum(128) | bin(4N) | csr(E)
    char* p = (char*)d_ws;
    u16* Y        = (u16*)p;            p += (size_t)N * FDIM * sizeof(u16);
    int* cnt      = (int*)p;            p += 8 * sizeof(int);
    int* deg      = (int*)p;            p += (size_t)N * sizeof(int);
    int* ncur     = (int*)p;            p += (size_t)N * sizeof(int);
    int* rowstart = (int*)p;            p += (size_t)N * sizeof(int);
    int* bsum     = (int*)p;            p += 128 * sizeof(int);
    int* bin      = (int*)p;            p += (size_t)4 * N * sizeof(int);
    int* csr      = (int*)p;

    hipMemsetAsync(cnt, 0, (size_t)(2 * N + 8) * sizeof(int), stream);

    int nodeBlocks = (N + 255) / 256;
    int edgeBlocks = (E + 255) / 256;
    binhist_kernel<<<max(nodeBlocks, edgeBlocks), 256, 0, stream>>>(
        lv, cnt, bin, eg, deg, N, E, nodeBlocks);

    int nb = (N + 1023) / 1024;   // <= 128 for N <= 131072
    scan_local<<<nb, 256, 0, stream>>>(deg, rowstart, bsum, N);
    scan_blocks<<<1, 128, 0, stream>>>(bsum, nb);

    fill_kernel<<<edgeBlocks, 256, 0, stream>>>(eg, lv, rowstart, bsum, ncur, csr, E);

    int blocksPerLevel = (N + NT - 1) / NT;
    transform_kernel<<<NLEV * blocksPerLevel, 256, 0, stream>>>(
        X, Wg, bg, cnt, bin, Y, N, blocksPerLevel);

    gather_kernel<<<(N + 7) / 8, 256, 0, stream>>>(
        X, (const uint2*)Y, rowstart, bsum, deg, csr, out, N);
}

// Round 6
// 88.893 us; speedup vs baseline: 7.8159x; 1.0030x over previous
//
#include <hip/hip_runtime.h>
#include <hip/hip_bf16.h>

#define FDIM 128
#define NLEV 4
#define NT   64   // nodes per transform block
#define WPAD 136  // padded row stride (u16) for LDS tiles: 272B -> 2-way bank alias (free)

typedef unsigned int  u32;
typedef unsigned short u16;

typedef __attribute__((ext_vector_type(8))) short short8v;  // 8 bf16 (4 VGPRs)
typedef __attribute__((ext_vector_type(4))) float f32x4;

__device__ __forceinline__ float bf_lo(u32 p) { return __uint_as_float(p << 16); }
__device__ __forceinline__ float bf_hi(u32 p) { return __uint_as_float(p & 0xffff0000u); }
__device__ __forceinline__ u16 f2bf(float f) {
    u32 u = __float_as_uint(f);
    u32 r = (u + 0x7fffu + ((u >> 16) & 1u)) >> 16;   // round-nearest-even
    return (u16)r;
}
__device__ __forceinline__ u32 pack2(float a, float b) {
    return (u32)f2bf(a) | ((u32)f2bf(b) << 16);
}

// ---- K0: fast zero (hipMemsetAsync's fill kernel costs 40us for 781KB!) ----
__global__ __launch_bounds__(256) void zero_kernel(int4* __restrict__ p, int n4) {
    int i = blockIdx.x * 256 + threadIdx.x;
    int stride = gridDim.x * 256;
    for (; i < n4; i += stride) p[i] = make_int4(0, 0, 0, 0);
}

// ---- K1: fused node-binning (first nodeBlocks blocks) + edge histogram (all blocks) ----
__global__ __launch_bounds__(256) void binhist_kernel(
    const int* __restrict__ lv, int* __restrict__ cnt, int* __restrict__ bin,
    const int* __restrict__ edges, int* __restrict__ deg,
    int N, int E, int nodeBlocks)
{
    int t = threadIdx.x;
    int b = blockIdx.x;

    // edge part: deg[hi]++ for valid edges (valid <=> lv[hi] > lv[lo])
    int e = b * 256 + t;
    if (e < E) {
        int lo = edges[2 * e];
        int hi = edges[2 * e + 1];
        if (lv[hi] > lv[lo]) atomicAdd(&deg[hi], 1);
    }

    // node part: bin by level, LDS histogram -> 4 global atomics/block
    if (b < nodeBlocks) {
        __shared__ int lcnt[NLEV];
        __shared__ int lbase[NLEV];
        if (t < NLEV) lcnt[t] = 0;
        __syncthreads();
        int n = b * 256 + t;
        int l = -1, pos = 0;
        if (n < N) {
            l = lv[n];
            if (l >= 0 && l < NLEV) pos = atomicAdd(&lcnt[l], 1);
            else l = -1;
        }
        __syncthreads();
        if (t < NLEV) lbase[t] = lcnt[t] ? atomicAdd(&cnt[t], lcnt[t]) : 0;
        __syncthreads();
        if (l >= 0) bin[l * N + lbase[l] + pos] = n;
    }
}

// ---- K2a: per-1024-chunk local exclusive scan + chunk totals ----
__global__ __launch_bounds__(256) void scan_local(const int* __restrict__ deg,
                                                  int* __restrict__ rowstart,
                                                  int* __restrict__ bsum, int N) {
    __shared__ int part[256];
    int t = threadIdx.x;
    int base = blockIdx.x * 1024 + t * 4;
    int v[4];
    #pragma unroll
    for (int k = 0; k < 4; ++k) v[k] = (base + k < N) ? deg[base + k] : 0;
    int s = v[0] + v[1] + v[2] + v[3];
    part[t] = s;
    __syncthreads();
    for (int off = 1; off < 256; off <<= 1) {      // Hillis-Steele inclusive
        int x = (t >= off) ? part[t - off] : 0;
        __syncthreads();
        part[t] += x;
        __syncthreads();
    }
    if (t == 255) bsum[blockIdx.x] = part[255];
    int run = part[t] - s;
    #pragma unroll
    for (int k = 0; k < 4; ++k) {
        if (base + k < N) rowstart[base + k] = run;
        run += v[k];
    }
}

// ---- K2b: exclusive scan of chunk totals (nb <= 128) ----
__global__ __launch_bounds__(128) void scan_blocks(int* __restrict__ bsum, int nb) {
    __shared__ int s[128];
    int t = threadIdx.x;
    s[t] = (t < nb) ? bsum[t] : 0;
    __syncthreads();
    if (t == 0) {
        int run = 0;
        for (int i = 0; i < nb; ++i) { int v = s[i]; s[i] = run; run += v; }
    }
    __syncthreads();
    if (t < nb) bsum[t] = s[t];
}

// ---- K3: csr[rs(hi) + ncur[hi]++] = lo for valid edges (bsum folded) ----
__global__ __launch_bounds__(256) void fill_kernel(const int* __restrict__ edges,
                                                   const int* __restrict__ lv,
                                                   const int* __restrict__ rowstart,
                                                   const int* __restrict__ bsum,
                                                   int* __restrict__ ncur,
                                                   int* __restrict__ csr, int E) {
    int e = blockIdx.x * 256 + threadIdx.x;
    if (e >= E) return;
    int lo = edges[2 * e];
    int hi = edges[2 * e + 1];
    if (lv[hi] > lv[lo]) {
        int s = rowstart[hi] + bsum[hi >> 10] + atomicAdd(&ncur[hi], 1);
        csr[s] = lo;
    }
}

// ---- K4 (MFMA): Y[n] = bf16( 0.2*(X[n] @ W[l].T + b[l]) ) for binned nodes ----
__global__ __launch_bounds__(256) void transform_kernel(
    const float* __restrict__ X, const float* __restrict__ Wg,
    const float* __restrict__ bg, const int* __restrict__ cnt,
    const int* __restrict__ bin, u16* __restrict__ Y, int N, int blocksPerLevel)
{
    __shared__ __align__(16) u16 Wt[FDIM][WPAD];  // W[l] bf16 row-major, padded
    __shared__ __align__(16) u16 Xt[NT][WPAD];    // X tile bf16 row-major; reused for Y out
    __shared__ int nodes_s[NT];

    int l     = blockIdx.x / blocksPerLevel;
    int chunk = blockIdx.x % blocksPerLevel;
    int m_total = cnt[l];
    int base = chunk * NT;
    if (base >= m_total) return;
    int m = min(NT, m_total - base);
    int t = threadIdx.x;

    if (t < NT) nodes_s[t] = (t < m) ? bin[l * N + base + t] : -1;
    __syncthreads();

    const float4* Wl4 = (const float4*)(Wg + (size_t)l * FDIM * FDIM);
    #pragma unroll
    for (int k = 0; k < 16; ++k) {
        int flat4 = t + k * 256;
        int row = flat4 >> 5;
        int c4  = flat4 & 31;
        float4 v = Wl4[flat4];
        *(uint2*)&Wt[row][c4 * 4] = make_uint2(pack2(v.x, v.y), pack2(v.z, v.w));
    }
    #pragma unroll
    for (int k = 0; k < 8; ++k) {
        int flat4 = t + k * 256;
        int row = flat4 >> 5;
        int c4  = flat4 & 31;
        int node = nodes_s[row];
        float4 v = (node >= 0) ? ((const float4*)(X + (size_t)node * FDIM))[c4]
                               : make_float4(0.f, 0.f, 0.f, 0.f);
        *(uint2*)&Xt[row][c4 * 4] = make_uint2(pack2(v.x, v.y), pack2(v.z, v.w));
    }
    __syncthreads();

    int wid  = t >> 6;
    int lane = t & 63;
    int arow = lane & 15;
    int kgrp = lane >> 4;

    f32x4 acc[8];
    #pragma unroll
    for (int ft = 0; ft < 8; ++ft) acc[ft] = (f32x4){0.f, 0.f, 0.f, 0.f};

    #pragma unroll
    for (int kstep = 0; kstep < 4; ++kstep) {
        int k0 = kstep * 32 + kgrp * 8;
        short8v a = *(const short8v*)&Xt[wid * 16 + arow][k0];
        #pragma unroll
        for (int ft = 0; ft < 8; ++ft) {
            short8v b = *(const short8v*)&Wt[ft * 16 + arow][k0];
            acc[ft] = __builtin_amdgcn_mfma_f32_16x16x32_bf16(a, b, acc[ft], 0, 0, 0);
        }
    }

    const float* bl = bg + l * FDIM;
    #pragma unroll
    for (int ft = 0; ft < 8; ++ft) {
        float bv = bl[ft * 16 + arow];
        #pragma unroll
        for (int reg = 0; reg < 4; ++reg) {
            int r = wid * 16 + kgrp * 4 + reg;
            Xt[r][ft * 16 + arow] = f2bf(0.2f * (acc[ft][reg] + bv));
        }
    }
    __syncthreads();

    #pragma unroll
    for (int k = 0; k < 4; ++k) {
        int flat16 = t + k * 256;
        int row = flat16 >> 4;
        int c   = flat16 & 15;
        int node = nodes_s[row];
        if (node >= 0)
            *(uint4*)&Y[(size_t)node * FDIM + c * 8] = *(const uint4*)&Xt[row][c * 8];
    }
}

// ---- K5: gather. Half-wave (32 lanes) per node; batch-4 Y loads for MLP ----
__global__ __launch_bounds__(256) void gather_kernel(
    const float* __restrict__ X, const uint2* __restrict__ Yp,
    const int* __restrict__ rowstart, const int* __restrict__ bsum,
    const int* __restrict__ deg, const int* __restrict__ csr,
    float* __restrict__ out, int N)
{
    int wid  = threadIdx.x >> 6;
    int lane = threadIdx.x & 63;
    int hl = lane >> 5;          // half: 0 or 1
    int sl = lane & 31;          // sub-lane within half
    int node = blockIdx.x * 8 + wid * 2 + hl;
    if (node >= N) return;

    float4 xv = *(const float4*)&X[(size_t)node * FDIM + sl * 4];
    int row = rowstart[node] + bsum[node >> 10];
    int d   = deg[node];

    float a0 = 0.f, a1 = 0.f, a2 = 0.f, a3 = 0.f;
    for (int base = 0; base < d; base += 32) {
        int c = min(32, d - base);
        int myLo = (sl < c) ? csr[row + base + sl] : 0;
        for (int i = 0; i < c; i += 4) {
            int b = min(4, c - i);
            uint2 p[4];
            #pragma unroll
            for (int j = 0; j < 4; ++j) {
                if (j < b) {
                    int lo = __shfl(myLo, hl * 32 + i + j, 64);
                    p[j] = Yp[(size_t)lo * (FDIM / 4) + sl];   // 8B/lane, 256B/edge
                }
            }
            #pragma unroll
            for (int j = 0; j < 4; ++j) {
                if (j < b) {
                    a0 += bf_lo(p[j].x); a1 += bf_hi(p[j].x);
                    a2 += bf_lo(p[j].y); a3 += bf_hi(p[j].y);
                }
            }
        }
    }
    float4 o = make_float4(xv.x + a0, xv.y + a1, xv.z + a2, xv.w + a3);
    *(float4*)&out[(size_t)node * FDIM + sl * 4] = o;
}

extern "C" void kernel_launch(void* const* d_in, const int* in_sizes, int n_in,
                              void* d_out, int out_size, void* d_ws, size_t ws_size,
                              hipStream_t stream) {
    const float* X  = (const float*)d_in[0];
    const float* Wg = (const float*)d_in[1];
    const float* bg = (const float*)d_in[2];
    const int*   lv = (const int*)d_in[3];
    const int*   eg = (const int*)d_in[4];
    float* out = (float*)d_out;

    int N = in_sizes[3];
    int E = in_sizes[4] / 2;

    // workspace: Y (bf16 N*F) | cnt(8) deg(N) ncur(N) [zeroed together] | rowstart(N) | bsum(128) | bin(4N) | csr(E)
    char* p = (char*)d_ws;
    u16* Y        = (u16*)p;            p += (size_t)N * FDIM * sizeof(u16);
    int* cnt      = (int*)p;            p += 8 * sizeof(int);
    int* deg      = (int*)p;            p += (size_t)N * sizeof(int);
    int* ncur     = (int*)p;            p += (size_t)N * sizeof(int);
    int* rowstart = (int*)p;            p += (size_t)N * sizeof(int);
    int* bsum     = (int*)p;            p += 128 * sizeof(int);
    int* bin      = (int*)p;            p += (size_t)4 * N * sizeof(int);
    int* csr      = (int*)p;

    // zero cnt+deg+ncur with our own kernel: hipMemsetAsync's fill kernel
    // measured 40us for 781KB (20 GB/s, latency-bound tiny grid).
    int nzero4 = (2 * N + 8) / 4;   // (2N+8) ints, divisible by 4
    zero_kernel<<<196, 256, 0, stream>>>((int4*)cnt, nzero4);

    int nodeBlocks = (N + 255) / 256;
    int edgeBlocks = (E + 255) / 256;
    binhist_kernel<<<max(nodeBlocks, edgeBlocks), 256, 0, stream>>>(
        lv, cnt, bin, eg, deg, N, E, nodeBlocks);

    int nb = (N + 1023) / 1024;   // <= 128 for N <= 131072
    scan_local<<<nb, 256, 0, stream>>>(deg, rowstart, bsum, N);
    scan_blocks<<<1, 128, 0, stream>>>(bsum, nb);

    fill_kernel<<<edgeBlocks, 256, 0, stream>>>(eg, lv, rowstart, bsum, ncur, csr, E);

    int blocksPerLevel = (N + NT - 1) / NT;
    transform_kernel<<<NLEV * blocksPerLevel, 256, 0, stream>>>(
        X, Wg, bg, cnt, bin, Y, N, blocksPerLevel);

    gather_kernel<<<(N + 7) / 8, 256, 0, stream>>>(
        X, (const uint2*)Y, rowstart, bsum, deg, csr, out, N);
}